// Round 5
// baseline (648.370 us; speedup 1.0000x reference)
//
#include <hip/hip_runtime.h>
#include <hip/hip_bf16.h>
#include <cstdint>
#include <cstddef>

#define DIM 1024
#define B_SZ 32
#define L_SZ 2048

#define BM 128
#define BN 128

// pre_kernel block-range split (no more ctx conversion -- it's inline in gemm)
#define HT_BLOCKS  512
#define WA_BLOCKS  512

typedef __attribute__((ext_vector_type(8))) short bf16x8;
typedef __attribute__((ext_vector_type(4))) float floatx4;

static __device__ __forceinline__ unsigned cvt2_bf16_rne(float a, float b) {
    unsigned ua = __builtin_bit_cast(unsigned, a);
    unsigned ub = __builtin_bit_cast(unsigned, b);
    ua = (ua + 0x7FFFu + ((ua >> 16) & 1u)) >> 16;
    ub = (ub + 0x7FFFu + ((ub >> 16) & 1u)) >> 16;
    return ua | (ub << 16);
}

// round-half-up bf16 pack: 2 v_add + 1 v_perm. out = hi16(a+0x8000) | hi16(b+0x8000)<<16
static __device__ __forceinline__ unsigned pk2_bf16_rhu(float a, float b) {
    const unsigned ua = __builtin_bit_cast(unsigned, a) + 0x8000u;
    const unsigned ub = __builtin_bit_cast(unsigned, b) + 0x8000u;
    return __builtin_amdgcn_perm(ub, ua, 0x07060302u);  // bytes: ua.b2,ua.b3,ub.b2,ub.b3
}

// tanh(x) = 1 - 2/(e^{2x}+1)
static __device__ __forceinline__ float tanh_fast(float x) {
    float e = __expf(2.0f * x);
    return 1.0f - 2.0f * __builtin_amdgcn_rcpf(e + 1.0f);
}

// async global->LDS, 16B per lane; LDS dest = uniform base + lane*16
static __device__ __forceinline__ void gld_lds16(const void* g, void* lds) {
    __builtin_amdgcn_global_load_lds(
        (const __attribute__((address_space(1))) unsigned int*)g,
        (__attribute__((address_space(3))) unsigned int*)lds,
        16, 0, 0);
}

// ---------------------------------------------------------------------------
// pre_kernel: {ht_proj, Wa_s fp32->bf16, scores zero, weighted zero}.
// Block-uniform branch; 1024 blocks total, ~25 us.
// ---------------------------------------------------------------------------
__global__ __launch_bounds__(256) void pre_kernel(
    const float* __restrict__ x, const float* __restrict__ Wa,
    unsigned short* __restrict__ WaB,
    float* __restrict__ ht, float* __restrict__ scores,
    float* __restrict__ weighted)
{
    const int bid = blockIdx.x, t = threadIdx.x;

    if (bid < HT_BLOCKS) {
        // ---- ht_proj[b][k] = sum_d x[b][d]*Wa[k][d]; + zero scores
        const int lb = bid;                         // 0..511
        const int gi = lb * 256 + t;                // 0..131071
        if (gi < B_SZ * L_SZ) scores[gi] = 0.f;
        const int b = lb >> 4, kb = lb & 15;
        __shared__ float xs[DIM];
        for (int i = t; i < DIM; i += 256) xs[i] = x[b * DIM + i];
        __syncthreads();
        const int wave = t >> 6, lane = t & 63;
        const float4* xs4 = (const float4*)xs;
        for (int kk = 0; kk < 16; ++kk) {
            const int k = kb * 64 + wave * 16 + kk;
            const float4* wr = (const float4*)(Wa + (size_t)k * (2 * DIM));
            float s = 0.f;
            #pragma unroll
            for (int d = 0; d < DIM / 4; d += 64) {
                const float4 w4 = wr[d + lane];
                const float4 x4 = xs4[d + lane];
                s += w4.x * x4.x + w4.y * x4.y + w4.z * x4.z + w4.w * x4.w;
            }
            #pragma unroll
            for (int off = 32; off > 0; off >>= 1) s += __shfl_xor(s, off);
            if (lane == 0) ht[b * DIM + k] = s;
        }
    } else {
        // ---- Wa_s[k][d] = Wa[k][1024+d] -> bf16 (RNE); + zero weighted
        const int lb = bid - HT_BLOCKS;                // 0..511
        const int i = lb * 256 + t;                    // 131072 chunks of 8
        if (i < B_SZ * DIM) weighted[i] = 0.f;
        const int k = i >> 7, dc = i & 127;
        const float* s = Wa + (size_t)k * (2 * DIM) + DIM + dc * 8;
        const float4 a = ((const float4*)s)[0];
        const float4 b4 = ((const float4*)s)[1];
        uint4 o;
        o.x = cvt2_bf16_rne(a.x, a.y);
        o.y = cvt2_bf16_rne(a.z, a.w);
        o.z = cvt2_bf16_rne(b4.x, b4.y);
        o.w = cvt2_bf16_rne(b4.z, b4.w);
        ((uint4*)(WaB + (size_t)k * DIM + dc * 8))[0] = o;
    }
}

// ---------------------------------------------------------------------------
// bf16 GEMM + fused tanh/Va epilogue, A converted INLINE from fp32 ctx.
//   A: global fp32 float4 loads -> round-half-up pack -> ds_write_b64 into
//      the SAME swizzled bf16 layout as R2 (LDS traffic unchanged vs R2).
//   B: pre-converted bf16 (2 MB, L2-hot), staged via global_load_lds w=16.
// LDS 32 KB, BK=64, 0-conflict XOR chunk swizzle on both operands.
// ---------------------------------------------------------------------------
__global__ __launch_bounds__(256) void gemm_score_f32a(
    const float* __restrict__ A, const unsigned short* __restrict__ Bm,
    const float* __restrict__ Va, const float* __restrict__ ht,
    float* __restrict__ scores)
{
    __shared__ __align__(16) unsigned short As[BM * 64];
    __shared__ __align__(16) unsigned short Bs[BN * 64];
    const int t = threadIdx.x;
    const int n0 = blockIdx.x * BN;
    const int m0 = blockIdx.y * BM;
    const int lane = t & 63, wave = t >> 6;
    const int l15 = lane & 15, quad = lane >> 4;
    const int wm = (wave >> 1) * 64, wn = (wave & 1) * 64;

    // ---- B staging map (gld16): wave covers rows [wave*32, +32), 8 rows/instr
    const int lrB = lane >> 3;                // 0..7 local row
    const int lcB = (lane & 7) ^ lrB;         // swizzled source chunk
    const size_t bRow = (size_t)(n0 + wave * 32 + lrB);

    // ---- A staging map (regs): per q, wave covers 4 rows x 16 f32-chunks(16B)
    const int lrA = lane >> 4;                // 0..3 local row within q-group
    const int ccA = lane & 15;                // f32 16B-chunk index (4 floats)
    const size_t aRowBase = (size_t)(m0 + wave * 32 + lrA);
    // dest: bf16 16B-chunk c = ccA>>1, half h = ccA&1, swizzle c^(r&7)
    const int hA = ccA & 1;

    floatx4 acc[4][4];
    #pragma unroll
    for (int i = 0; i < 4; ++i)
        #pragma unroll
        for (int j = 0; j < 4; ++j) acc[i][j] = (floatx4)0.f;

    for (int k0 = 0; k0 < DIM; k0 += 64) {
        // B tile -> LDS (async DMA, no regs)
        #pragma unroll
        for (int q = 0; q < 4; ++q)
            gld_lds16(Bm + (bRow + q * 8) * DIM + k0 + lcB * 8,
                      &Bs[(wave * 32 + q * 8) * 64]);

        // A tile: fp32 -> bf16 in regs -> LDS
        #pragma unroll
        for (int q = 0; q < 8; ++q) {
            const int r = wave * 32 + q * 4 + lrA;
            const float4 v = *(const float4*)(A + (aRowBase + q * 4) * DIM + k0 + ccA * 4);
            const uint2 p = make_uint2(pk2_bf16_rhu(v.x, v.y), pk2_bf16_rhu(v.z, v.w));
            const int c = ((ccA >> 1) ^ (r & 7));
            *(uint2*)&As[r * 64 + c * 8 + hA * 4] = p;
        }
        __syncthreads();   // drains vmcnt (B DMA) + lgkm (A writes)

        bf16x8 af[2][4], bv[2][4];
        #pragma unroll
        for (int kb = 0; kb < 2; ++kb) {
            #pragma unroll
            for (int i = 0; i < 4; ++i) {
                const int r = wm + i * 16 + l15;
                const int c = (kb * 4 + quad) ^ (r & 7);
                af[kb][i] = *(const bf16x8*)&As[r * 64 + c * 8];
            }
            #pragma unroll
            for (int j = 0; j < 4; ++j) {
                const int r = wn + j * 16 + l15;
                const int c = (kb * 4 + quad) ^ (r & 7);
                bv[kb][j] = *(const bf16x8*)&Bs[r * 64 + c * 8];
            }
        }
        #pragma unroll
        for (int kb = 0; kb < 2; ++kb)
            #pragma unroll
            for (int i = 0; i < 4; ++i)
                #pragma unroll
                for (int j = 0; j < 4; ++j)
                    acc[i][j] = __builtin_amdgcn_mfma_f32_16x16x32_bf16(
                        af[kb][i], bv[kb][j], acc[i][j], 0, 0, 0);
        __syncthreads();
    }

    // epilogue: scores[m] += sum_n tanh(acc + ht[n]) * Va[n]
    // C/D layout: n = lane&15, m = quad*4 + reg
    const int bb = m0 >> 11;
    float htv[4], vav[4];
    #pragma unroll
    for (int j = 0; j < 4; ++j) {
        const int ng = n0 + wn + j * 16 + l15;
        htv[j] = ht[bb * DIM + ng];
        vav[j] = Va[ng];
    }
    #pragma unroll
    for (int i = 0; i < 4; ++i) {
        #pragma unroll
        for (int r = 0; r < 4; ++r) {
            float s = 0.f;
            #pragma unroll
            for (int j = 0; j < 4; ++j)
                s += tanh_fast(acc[i][j][r] + htv[j]) * vav[j];
            s += __shfl_xor(s, 8);
            s += __shfl_xor(s, 4);
            s += __shfl_xor(s, 2);
            s += __shfl_xor(s, 1);
            if (l15 == 0)
                atomicAdd(&scores[m0 + wm + i * 16 + quad * 4 + r], s);
        }
    }
}

// ---------------------------------------------------------------------------
// post_kernel: softmax (stats recomputed per block -- deterministic) + attn
// write + weighted accumulate, reading ctx fp32 directly.
// grid (B_SZ, 16), 256 threads; block (b,slice) owns l in [slice*128, +128).
// ---------------------------------------------------------------------------
__global__ __launch_bounds__(256) void post_kernel(
    const float* __restrict__ scores, const float* __restrict__ ctx,
    float* __restrict__ attn, float* __restrict__ weighted)
{
    const int b = blockIdx.x, slice = blockIdx.y, t = threadIdx.x;
    const float* sc = scores + b * L_SZ;
    __shared__ float red[256];
    __shared__ float att[128];

    float m = -1e30f;
    for (int l = t; l < L_SZ; l += 256) m = fmaxf(m, sc[l]);
    red[t] = m; __syncthreads();
    for (int s = 128; s > 0; s >>= 1) { if (t < s) red[t] = fmaxf(red[t], red[t + s]); __syncthreads(); }
    m = red[0]; __syncthreads();
    float sum = 0.f;
    for (int l = t; l < L_SZ; l += 256) sum += __expf(sc[l] - m);
    red[t] = sum; __syncthreads();
    for (int s = 128; s > 0; s >>= 1) { if (t < s) red[t] += red[t + s]; __syncthreads(); }
    const float inv = 1.0f / red[0];

    const int l0 = slice * 128;
    if (t < 128) {
        const float av = __expf(sc[l0 + t] - m) * inv;
        att[t] = av;
        attn[b * L_SZ + l0 + t] = av;
    }
    __syncthreads();

    const float* cb = ctx + ((size_t)b * L_SZ + l0) * DIM + t * 4;
    float4 w = make_float4(0.f, 0.f, 0.f, 0.f);
    for (int l = 0; l < 128; ++l) {
        const float a = att[l];
        const float4 c = *(const float4*)(cb + (size_t)l * DIM);
        w.x += a * c.x; w.y += a * c.y; w.z += a * c.z; w.w += a * c.w;
    }
    float* o = weighted + b * DIM + t * 4;
    atomicAdd(o + 0, w.x);
    atomicAdd(o + 1, w.y);
    atomicAdd(o + 2, w.z);
    atomicAdd(o + 3, w.w);
}

// ---------------------------------------------------------------------------
// fallback path (ws too small for even 2.4 MB): fp32-staging GEMM
// ---------------------------------------------------------------------------
#define LDS_STRIDE 40
__global__ __launch_bounds__(256) void ht_kernel_fb(const float* __restrict__ x,
                                                    const float* __restrict__ Wa,
                                                    float* __restrict__ ht,
                                                    float* __restrict__ scores,
                                                    float* __restrict__ weighted) {
    const int b = blockIdx.x, kb = blockIdx.y, t = threadIdx.x;
    const int gidx = (b * 16 + kb) * 256 + t;
    if (gidx < B_SZ * L_SZ) scores[gidx] = 0.f;
    if (gidx < B_SZ * DIM) weighted[gidx] = 0.f;
    __shared__ float xs[DIM];
    for (int i = t; i < DIM; i += 256) xs[i] = x[b * DIM + i];
    __syncthreads();
    const int wave = t >> 6, lane = t & 63;
    for (int kk = 0; kk < 16; ++kk) {
        const int k = kb * 64 + wave * 16 + kk;
        const float* wr = Wa + (size_t)k * (2 * DIM);
        float s = 0.f;
        #pragma unroll
        for (int d = 0; d < DIM; d += 64) s += xs[d + lane] * wr[d + lane];
        #pragma unroll
        for (int off = 32; off > 0; off >>= 1) s += __shfl_xor(s, off);
        if (lane == 0) ht[b * DIM + k] = s;
    }
}

__global__ __launch_bounds__(256, 2) void gemm_score_kernel(
    const float* __restrict__ ctx, const float* __restrict__ Wa,
    const float* __restrict__ Va, const float* __restrict__ ht,
    float* __restrict__ scores)
{
    __shared__ unsigned short As[BM * LDS_STRIDE];
    __shared__ unsigned short Bs[BN * LDS_STRIDE];
    const int t = threadIdx.x;
    const int n0 = blockIdx.x * BN;
    const int m0 = blockIdx.y * BM;
    const int lane = t & 63, wave = t >> 6;
    const int l15 = lane & 15, quad = lane >> 4;
    const int wm = (wave >> 1) * 64, wn = (wave & 1) * 64;
    const int srow = t >> 3;
    const int scol = (t & 7) * 4;
    const float* aBase = ctx + (size_t)(m0 + srow) * DIM + scol;
    const float* bBase = Wa + (size_t)(n0 + srow) * (2 * DIM) + DIM + scol;

    floatx4 acc[4][4];
    #pragma unroll
    for (int i = 0; i < 4; ++i)
        #pragma unroll
        for (int j = 0; j < 4; ++j) acc[i][j] = (floatx4)0.f;

    for (int k0 = 0; k0 < DIM; k0 += 32) {
        __syncthreads();
        #pragma unroll
        for (int r = 0; r < 4; ++r) {
            const float4 va = *(const float4*)(aBase + (size_t)(r * 32) * DIM + k0);
            const float4 vb = *(const float4*)(bBase + (size_t)(r * 32) * (2 * DIM) + k0);
            *(uint2*)&As[(srow + r * 32) * LDS_STRIDE + scol] =
                make_uint2(cvt2_bf16_rne(va.x, va.y), cvt2_bf16_rne(va.z, va.w));
            *(uint2*)&Bs[(srow + r * 32) * LDS_STRIDE + scol] =
                make_uint2(cvt2_bf16_rne(vb.x, vb.y), cvt2_bf16_rne(vb.z, vb.w));
        }
        __syncthreads();
        bf16x8 af[4], bfr[4];
        #pragma unroll
        for (int i = 0; i < 4; ++i)
            af[i] = *(const bf16x8*)&As[(wm + i * 16 + l15) * LDS_STRIDE + quad * 8];
        #pragma unroll
        for (int j = 0; j < 4; ++j)
            bfr[j] = *(const bf16x8*)&Bs[(wn + j * 16 + l15) * LDS_STRIDE + quad * 8];
        #pragma unroll
        for (int i = 0; i < 4; ++i)
            #pragma unroll
            for (int j = 0; j < 4; ++j)
                acc[i][j] = __builtin_amdgcn_mfma_f32_16x16x32_bf16(af[i], bfr[j], acc[i][j], 0, 0, 0);
    }
    const int bb = m0 >> 11;
    float htv[4], vav[4];
    #pragma unroll
    for (int j = 0; j < 4; ++j) {
        const int ng = n0 + wn + j * 16 + l15;
        htv[j] = ht[bb * DIM + ng];
        vav[j] = Va[ng];
    }
    #pragma unroll
    for (int i = 0; i < 4; ++i) {
        #pragma unroll
        for (int r = 0; r < 4; ++r) {
            float s = 0.f;
            #pragma unroll
            for (int j = 0; j < 4; ++j)
                s += tanh_fast(acc[i][j][r] + htv[j]) * vav[j];
            s += __shfl_xor(s, 8);
            s += __shfl_xor(s, 4);
            s += __shfl_xor(s, 2);
            s += __shfl_xor(s, 1);
            if (l15 == 0)
                atomicAdd(&scores[m0 + wm + i * 16 + quad * 4 + r], s);
        }
    }
}

extern "C" void kernel_launch(void* const* d_in, const int* in_sizes, int n_in,
                              void* d_out, int out_size, void* d_ws, size_t ws_size,
                              hipStream_t stream) {
    const float* x   = (const float*)d_in[0];   // 32 x 1024
    const float* ctx = (const float*)d_in[1];   // 32 x 2048 x 1024
    const float* Wa  = (const float*)d_in[2];   // 1024 x 2048
    const float* Va  = (const float*)d_in[3];   // 1 x 1024

    float* out      = (float*)d_out;
    float* weighted = out;                      // 32*1024
    float* attn     = out + B_SZ * DIM;         // 32*2048

    float* scores = (float*)d_ws;               // 256 KB
    float* ht     = scores + B_SZ * L_SZ;       // 128 KB

    const size_t base = (size_t)(B_SZ * L_SZ + B_SZ * DIM) * sizeof(float);
    const size_t need = base + (size_t)DIM * DIM * 2;   // + Wa_s bf16 (2 MB)

    if (ws_size >= need) {
        unsigned short* WaB = (unsigned short*)((char*)d_ws + base);
        pre_kernel<<<HT_BLOCKS + WA_BLOCKS, 256, 0, stream>>>(
            x, Wa, WaB, ht, scores, weighted);
        gemm_score_f32a<<<dim3(DIM / BN, (B_SZ * L_SZ) / BM), 256, 0, stream>>>(
            ctx, WaB, Va, ht, scores);
        post_kernel<<<dim3(B_SZ, 16), 256, 0, stream>>>(scores, ctx, attn, weighted);
    } else {
        ht_kernel_fb<<<dim3(B_SZ, 16), 256, 0, stream>>>(x, Wa, ht, scores, weighted);
        gemm_score_kernel<<<dim3(DIM / BN, (B_SZ * L_SZ) / BM), 256, 0, stream>>>(
            ctx, Wa, Va, ht, scores);
        post_kernel<<<dim3(B_SZ, 16), 256, 0, stream>>>(scores, ctx, attn, weighted);
    }
}

// Round 6
// 595.894 us; speedup vs baseline: 1.0881x; 1.0881x over previous
//
#include <hip/hip_runtime.h>
#include <hip/hip_bf16.h>
#include <cstdint>
#include <cstddef>

#define DIM 1024
#define B_SZ 32
#define L_SZ 2048

#define BM 128
#define BN 128

// pre_kernel block-range split
#define CVT_BLOCKS 8192
#define HT_BLOCKS  512
#define WA_BLOCKS  512

typedef __attribute__((ext_vector_type(8))) short bf16x8;
typedef __attribute__((ext_vector_type(4))) float floatx4;

static __device__ __forceinline__ unsigned cvt2_bf16_rne(float a, float b) {
    unsigned ua = __builtin_bit_cast(unsigned, a);
    unsigned ub = __builtin_bit_cast(unsigned, b);
    ua = (ua + 0x7FFFu + ((ua >> 16) & 1u)) >> 16;
    ub = (ub + 0x7FFFu + ((ub >> 16) & 1u)) >> 16;
    return ua | (ub << 16);
}

static __device__ __forceinline__ float bf2f(unsigned u16) {
    return __builtin_bit_cast(float, u16 << 16);
}

// tanh(x) = 1 - 2/(e^{2x}+1)
static __device__ __forceinline__ float tanh_fast(float x) {
    float e = __expf(2.0f * x);
    return 1.0f - 2.0f * __builtin_amdgcn_rcpf(e + 1.0f);
}

// async global->LDS, 16B per lane; LDS dest = uniform base + lane*16
static __device__ __forceinline__ void gld_lds16(const void* g, void* lds) {
    __builtin_amdgcn_global_load_lds(
        (const __attribute__((address_space(1))) unsigned int*)g,
        (__attribute__((address_space(3))) unsigned int*)lds,
        16, 0, 0);
}

// ---------------------------------------------------------------------------
// pre_kernel: ONE dispatch for {ctx fp32->bf16, ht_proj, Wa_s fp32->bf16,
// scores zero, weighted zero}. Branch is block-uniform (blockIdx split).
// ---------------------------------------------------------------------------
__global__ __launch_bounds__(256) void pre_kernel(
    const float* __restrict__ x, const float* __restrict__ ctx,
    const float* __restrict__ Wa,
    unsigned short* __restrict__ ctxB, unsigned short* __restrict__ WaB,
    float* __restrict__ ht, float* __restrict__ scores,
    float* __restrict__ weighted)
{
    const int bid = blockIdx.x, t = threadIdx.x;

    if (bid < CVT_BLOCKS) {
        // ---- ctx fp32 -> bf16: 16 floats/iter, 2x float4 load + 1x uint4 store
        const long n8 = (long)B_SZ * L_SZ * DIM / 8;        // 8.39M chunks
        const long stride = (long)CVT_BLOCKS * 256;
        for (long i = (long)bid * 256 + t; i < n8; i += stride) {
            const float4 a = ((const float4*)ctx)[i * 2];
            const float4 b = ((const float4*)ctx)[i * 2 + 1];
            uint4 o;
            o.x = cvt2_bf16_rne(a.x, a.y);
            o.y = cvt2_bf16_rne(a.z, a.w);
            o.z = cvt2_bf16_rne(b.x, b.y);
            o.w = cvt2_bf16_rne(b.z, b.w);
            ((uint4*)ctxB)[i] = o;
        }
    } else if (bid < CVT_BLOCKS + HT_BLOCKS) {
        // ---- ht_proj[b][k] = sum_d x[b][d]*Wa[k][d]; + zero scores
        const int lb = bid - CVT_BLOCKS;            // 0..511
        const int gi = lb * 256 + t;                // 0..131071
        if (gi < B_SZ * L_SZ) scores[gi] = 0.f;
        const int b = lb >> 4, kb = lb & 15;
        __shared__ float xs[DIM];
        for (int i = t; i < DIM; i += 256) xs[i] = x[b * DIM + i];
        __syncthreads();
        const int wave = t >> 6, lane = t & 63;
        const float4* xs4 = (const float4*)xs;
        for (int kk = 0; kk < 16; ++kk) {
            const int k = kb * 64 + wave * 16 + kk;
            const float4* wr = (const float4*)(Wa + (size_t)k * (2 * DIM));
            float s = 0.f;
            #pragma unroll
            for (int d = 0; d < DIM / 4; d += 64) {
                const float4 w4 = wr[d + lane];
                const float4 x4 = xs4[d + lane];
                s += w4.x * x4.x + w4.y * x4.y + w4.z * x4.z + w4.w * x4.w;
            }
            #pragma unroll
            for (int off = 32; off > 0; off >>= 1) s += __shfl_xor(s, off);
            if (lane == 0) ht[b * DIM + k] = s;
        }
    } else {
        // ---- Wa_s[k][d] = Wa[k][1024+d] -> bf16; + zero weighted
        const int lb = bid - CVT_BLOCKS - HT_BLOCKS;   // 0..511
        const int i = lb * 256 + t;                    // 131072 chunks of 8
        if (i < B_SZ * DIM) weighted[i] = 0.f;
        const int k = i >> 7, dc = i & 127;
        const float* s = Wa + (size_t)k * (2 * DIM) + DIM + dc * 8;
        const float4 a = ((const float4*)s)[0];
        const float4 b4 = ((const float4*)s)[1];
        uint4 o;
        o.x = cvt2_bf16_rne(a.x, a.y);
        o.y = cvt2_bf16_rne(a.z, a.w);
        o.z = cvt2_bf16_rne(b4.x, b4.y);
        o.w = cvt2_bf16_rne(b4.z, b4.w);
        ((uint4*)(WaB + (size_t)k * DIM + dc * 8))[0] = o;
    }
}

// ---------------------------------------------------------------------------
// R2-exact bf16 GEMM + fused tanh/Va epilogue (189 us, 0 bank conflicts).
// A and B both LDS-staged via global_load_lds width=16, XOR chunk-swizzled.
// DO NOT replace the DMA staging: direct-global B (R3) and inline fp32->bf16
// A (R5) both regressed >1.7x.
// ---------------------------------------------------------------------------
__global__ __launch_bounds__(256) void gemm_score_bf16(
    const unsigned short* __restrict__ A, const unsigned short* __restrict__ Bm,
    const float* __restrict__ Va, const float* __restrict__ ht,
    float* __restrict__ scores)
{
    __shared__ __align__(16) unsigned short As[BM * 64];
    __shared__ __align__(16) unsigned short Bs[BN * 64];
    const int t = threadIdx.x;
    const int n0 = blockIdx.x * BN;
    const int m0 = blockIdx.y * BM;
    const int lane = t & 63, wave = t >> 6;
    const int l15 = lane & 15, quad = lane >> 4;
    const int wm = (wave >> 1) * 64, wn = (wave & 1) * 64;

    const int lr = lane >> 3;                 // 0..7 local row
    const int lc = (lane & 7) ^ lr;           // swizzled source chunk
    const size_t aRow = (size_t)(m0 + wave * 32 + lr);
    const size_t bRow = (size_t)(n0 + wave * 32 + lr);

    floatx4 acc[4][4];
    #pragma unroll
    for (int i = 0; i < 4; ++i)
        #pragma unroll
        for (int j = 0; j < 4; ++j) acc[i][j] = (floatx4)0.f;

    for (int k0 = 0; k0 < DIM; k0 += 64) {
        #pragma unroll
        for (int q = 0; q < 4; ++q) {
            gld_lds16(A + (aRow + q * 8) * DIM + k0 + lc * 8,
                      &As[(wave * 32 + q * 8) * 64]);
            gld_lds16(Bm + (bRow + q * 8) * DIM + k0 + lc * 8,
                      &Bs[(wave * 32 + q * 8) * 64]);
        }
        __syncthreads();

        bf16x8 af[2][4], bv[2][4];
        #pragma unroll
        for (int kb = 0; kb < 2; ++kb) {
            #pragma unroll
            for (int i = 0; i < 4; ++i) {
                const int r = wm + i * 16 + l15;
                const int c = (kb * 4 + quad) ^ (r & 7);
                af[kb][i] = *(const bf16x8*)&As[r * 64 + c * 8];
            }
            #pragma unroll
            for (int j = 0; j < 4; ++j) {
                const int r = wn + j * 16 + l15;
                const int c = (kb * 4 + quad) ^ (r & 7);
                bv[kb][j] = *(const bf16x8*)&Bs[r * 64 + c * 8];
            }
        }
        #pragma unroll
        for (int kb = 0; kb < 2; ++kb)
            #pragma unroll
            for (int i = 0; i < 4; ++i)
                #pragma unroll
                for (int j = 0; j < 4; ++j)
                    acc[i][j] = __builtin_amdgcn_mfma_f32_16x16x32_bf16(
                        af[kb][i], bv[kb][j], acc[i][j], 0, 0, 0);
        __syncthreads();
    }

    // epilogue: scores[m] += sum_n tanh(acc + ht[n]) * Va[n]
    // C/D layout: n = lane&15, m = quad*4 + reg
    const int bb = m0 >> 11;
    float htv[4], vav[4];
    #pragma unroll
    for (int j = 0; j < 4; ++j) {
        const int ng = n0 + wn + j * 16 + l15;
        htv[j] = ht[bb * DIM + ng];
        vav[j] = Va[ng];
    }
    #pragma unroll
    for (int i = 0; i < 4; ++i) {
        #pragma unroll
        for (int r = 0; r < 4; ++r) {
            float s = 0.f;
            #pragma unroll
            for (int j = 0; j < 4; ++j)
                s += tanh_fast(acc[i][j][r] + htv[j]) * vav[j];
            s += __shfl_xor(s, 8);
            s += __shfl_xor(s, 4);
            s += __shfl_xor(s, 2);
            s += __shfl_xor(s, 1);
            if (l15 == 0)
                atomicAdd(&scores[m0 + wm + i * 16 + quad * 4 + r], s);
        }
    }
}

// ---------------------------------------------------------------------------
// post_kernel: softmax (stats recomputed per block -- deterministic, so all
// 16 blocks of row b agree) + attn slice write + weighted slice accumulate
// from bf16 ctx.
// ---------------------------------------------------------------------------
__global__ __launch_bounds__(256) void post_kernel(
    const float* __restrict__ scores, const unsigned short* __restrict__ ctxB,
    float* __restrict__ attn, float* __restrict__ weighted)
{
    const int b = blockIdx.x, slice = blockIdx.y, t = threadIdx.x;
    const float* sc = scores + b * L_SZ;
    __shared__ float red[256];
    __shared__ float att[128];

    float m = -1e30f;
    for (int l = t; l < L_SZ; l += 256) m = fmaxf(m, sc[l]);
    red[t] = m; __syncthreads();
    for (int s = 128; s > 0; s >>= 1) { if (t < s) red[t] = fmaxf(red[t], red[t + s]); __syncthreads(); }
    m = red[0]; __syncthreads();
    float sum = 0.f;
    for (int l = t; l < L_SZ; l += 256) sum += __expf(sc[l] - m);
    red[t] = sum; __syncthreads();
    for (int s = 128; s > 0; s >>= 1) { if (t < s) red[t] += red[t + s]; __syncthreads(); }
    const float inv = 1.0f / red[0];

    const int l0 = slice * 128;
    if (t < 128) {
        const float av = __expf(sc[l0 + t] - m) * inv;
        att[t] = av;
        attn[b * L_SZ + l0 + t] = av;
    }
    __syncthreads();

    const unsigned short* cb = ctxB + ((size_t)b * L_SZ + l0) * DIM + t * 4;
    float a0 = 0.f, a1 = 0.f, a2 = 0.f, a3 = 0.f;
    for (int l = 0; l < 128; ++l) {
        const float a = att[l];
        const uint2 v = *(const uint2*)(cb + (size_t)l * DIM);
        a0 += a * bf2f(v.x & 0xFFFFu);
        a1 += a * bf2f(v.x >> 16);
        a2 += a * bf2f(v.y & 0xFFFFu);
        a3 += a * bf2f(v.y >> 16);
    }
    float* o = weighted + b * DIM + t * 4;
    atomicAdd(o + 0, a0);
    atomicAdd(o + 1, a1);
    atomicAdd(o + 2, a2);
    atomicAdd(o + 3, a3);
}

// ---------------------------------------------------------------------------
// fallback path (ws too small): fp32-staging GEMM + separate aux kernels
// ---------------------------------------------------------------------------
#define LDS_STRIDE 40
__global__ __launch_bounds__(256) void ht_kernel_fb(const float* __restrict__ x,
                                                    const float* __restrict__ Wa,
                                                    float* __restrict__ ht,
                                                    float* __restrict__ scores,
                                                    float* __restrict__ weighted) {
    const int b = blockIdx.x, kb = blockIdx.y, t = threadIdx.x;
    const int gidx = (b * 16 + kb) * 256 + t;
    if (gidx < B_SZ * L_SZ) scores[gidx] = 0.f;
    if (gidx < B_SZ * DIM) weighted[gidx] = 0.f;
    __shared__ float xs[DIM];
    for (int i = t; i < DIM; i += 256) xs[i] = x[b * DIM + i];
    __syncthreads();
    const int wave = t >> 6, lane = t & 63;
    for (int kk = 0; kk < 16; ++kk) {
        const int k = kb * 64 + wave * 16 + kk;
        const float* wr = Wa + (size_t)k * (2 * DIM);
        float s = 0.f;
        #pragma unroll
        for (int d = 0; d < DIM; d += 64) s += xs[d + lane] * wr[d + lane];
        #pragma unroll
        for (int off = 32; off > 0; off >>= 1) s += __shfl_xor(s, off);
        if (lane == 0) ht[b * DIM + k] = s;
    }
}

__global__ __launch_bounds__(256, 2) void gemm_score_kernel(
    const float* __restrict__ ctx, const float* __restrict__ Wa,
    const float* __restrict__ Va, const float* __restrict__ ht,
    float* __restrict__ scores)
{
    __shared__ unsigned short As[BM * LDS_STRIDE];
    __shared__ unsigned short Bs[BN * LDS_STRIDE];
    const int t = threadIdx.x;
    const int n0 = blockIdx.x * BN;
    const int m0 = blockIdx.y * BM;
    const int lane = t & 63, wave = t >> 6;
    const int l15 = lane & 15, quad = lane >> 4;
    const int wm = (wave >> 1) * 64, wn = (wave & 1) * 64;
    const int srow = t >> 3;
    const int scol = (t & 7) * 4;
    const float* aBase = ctx + (size_t)(m0 + srow) * DIM + scol;
    const float* bBase = Wa + (size_t)(n0 + srow) * (2 * DIM) + DIM + scol;

    floatx4 acc[4][4];
    #pragma unroll
    for (int i = 0; i < 4; ++i)
        #pragma unroll
        for (int j = 0; j < 4; ++j) acc[i][j] = (floatx4)0.f;

    for (int k0 = 0; k0 < DIM; k0 += 32) {
        __syncthreads();
        #pragma unroll
        for (int r = 0; r < 4; ++r) {
            const float4 va = *(const float4*)(aBase + (size_t)(r * 32) * DIM + k0);
            const float4 vb = *(const float4*)(bBase + (size_t)(r * 32) * (2 * DIM) + k0);
            *(uint2*)&As[(srow + r * 32) * LDS_STRIDE + scol] =
                make_uint2(cvt2_bf16_rne(va.x, va.y), cvt2_bf16_rne(va.z, va.w));
            *(uint2*)&Bs[(srow + r * 32) * LDS_STRIDE + scol] =
                make_uint2(cvt2_bf16_rne(vb.x, vb.y), cvt2_bf16_rne(vb.z, vb.w));
        }
        __syncthreads();
        bf16x8 af[4], bfr[4];
        #pragma unroll
        for (int i = 0; i < 4; ++i)
            af[i] = *(const bf16x8*)&As[(wm + i * 16 + l15) * LDS_STRIDE + quad * 8];
        #pragma unroll
        for (int j = 0; j < 4; ++j)
            bfr[j] = *(const bf16x8*)&Bs[(wn + j * 16 + l15) * LDS_STRIDE + quad * 8];
        #pragma unroll
        for (int i = 0; i < 4; ++i)
            #pragma unroll
            for (int j = 0; j < 4; ++j)
                acc[i][j] = __builtin_amdgcn_mfma_f32_16x16x32_bf16(af[i], bfr[j], acc[i][j], 0, 0, 0);
    }
    const int bb = m0 >> 11;
    float htv[4], vav[4];
    #pragma unroll
    for (int j = 0; j < 4; ++j) {
        const int ng = n0 + wn + j * 16 + l15;
        htv[j] = ht[bb * DIM + ng];
        vav[j] = Va[ng];
    }
    #pragma unroll
    for (int i = 0; i < 4; ++i) {
        #pragma unroll
        for (int r = 0; r < 4; ++r) {
            float s = 0.f;
            #pragma unroll
            for (int j = 0; j < 4; ++j)
                s += tanh_fast(acc[i][j][r] + htv[j]) * vav[j];
            s += __shfl_xor(s, 8);
            s += __shfl_xor(s, 4);
            s += __shfl_xor(s, 2);
            s += __shfl_xor(s, 1);
            if (l15 == 0)
                atomicAdd(&scores[m0 + wm + i * 16 + quad * 4 + r], s);
        }
    }
}

__global__ __launch_bounds__(256) void post_kernel_fb(
    const float* __restrict__ scores, const float* __restrict__ ctx,
    float* __restrict__ attn, float* __restrict__ weighted)
{
    const int b = blockIdx.x, slice = blockIdx.y, t = threadIdx.x;
    const float* sc = scores + b * L_SZ;
    __shared__ float red[256];
    __shared__ float att[128];
    float m = -1e30f;
    for (int l = t; l < L_SZ; l += 256) m = fmaxf(m, sc[l]);
    red[t] = m; __syncthreads();
    for (int s = 128; s > 0; s >>= 1) { if (t < s) red[t] = fmaxf(red[t], red[t + s]); __syncthreads(); }
    m = red[0]; __syncthreads();
    float sum = 0.f;
    for (int l = t; l < L_SZ; l += 256) sum += __expf(sc[l] - m);
    red[t] = sum; __syncthreads();
    for (int s = 128; s > 0; s >>= 1) { if (t < s) red[t] += red[t + s]; __syncthreads(); }
    const float inv = 1.0f / red[0];
    const int l0 = slice * 128;
    if (t < 128) {
        const float av = __expf(sc[l0 + t] - m) * inv;
        att[t] = av;
        attn[b * L_SZ + l0 + t] = av;
    }
    __syncthreads();
    const float* cb = ctx + ((size_t)b * L_SZ + l0) * DIM + t * 4;
    float4 w = make_float4(0.f, 0.f, 0.f, 0.f);
    for (int l = 0; l < 128; ++l) {
        const float a = att[l];
        const float4 c = *(const float4*)(cb + (size_t)l * DIM);
        w.x += a * c.x; w.y += a * c.y; w.z += a * c.z; w.w += a * c.w;
    }
    float* o = weighted + b * DIM + t * 4;
    atomicAdd(o + 0, w.x);
    atomicAdd(o + 1, w.y);
    atomicAdd(o + 2, w.z);
    atomicAdd(o + 3, w.w);
}

extern "C" void kernel_launch(void* const* d_in, const int* in_sizes, int n_in,
                              void* d_out, int out_size, void* d_ws, size_t ws_size,
                              hipStream_t stream) {
    const float* x   = (const float*)d_in[0];   // 32 x 1024
    const float* ctx = (const float*)d_in[1];   // 32 x 2048 x 1024
    const float* Wa  = (const float*)d_in[2];   // 1024 x 2048
    const float* Va  = (const float*)d_in[3];   // 1 x 1024

    float* out      = (float*)d_out;
    float* weighted = out;                      // 32*1024
    float* attn     = out + B_SZ * DIM;         // 32*2048

    float* scores = (float*)d_ws;               // 256 KB
    float* ht     = scores + B_SZ * L_SZ;       // 128 KB

    const size_t base = (size_t)(B_SZ * L_SZ + B_SZ * DIM) * sizeof(float);
    const size_t need = base + (size_t)DIM * DIM * 2            // Wa_s bf16: 2 MB
                      + (size_t)B_SZ * L_SZ * DIM * 2;          // ctx bf16: 128 MB

    if (ws_size >= need) {
        unsigned short* WaB  = (unsigned short*)((char*)d_ws + base);
        unsigned short* ctxB = WaB + (size_t)DIM * DIM;
        pre_kernel<<<CVT_BLOCKS + HT_BLOCKS + WA_BLOCKS, 256, 0, stream>>>(
            x, ctx, Wa, ctxB, WaB, ht, scores, weighted);
        gemm_score_bf16<<<dim3(DIM / BN, (B_SZ * L_SZ) / BM), 256, 0, stream>>>(
            ctxB, WaB, Va, ht, scores);
        post_kernel<<<dim3(B_SZ, 16), 256, 0, stream>>>(scores, ctxB, attn, weighted);
    } else {
        ht_kernel_fb<<<dim3(B_SZ, 16), 256, 0, stream>>>(x, Wa, ht, scores, weighted);
        gemm_score_kernel<<<dim3(DIM / BN, (B_SZ * L_SZ) / BM), 256, 0, stream>>>(
            ctx, Wa, Va, ht, scores);
        post_kernel_fb<<<dim3(B_SZ, 16), 256, 0, stream>>>(scores, ctx, attn, weighted);
    }
}